// Round 12
// baseline (145.911 us; speedup 1.0000x reference)
//
#include <hip/hip_runtime.h>
#include <math.h>

// Problem constants (match reference)
#define GG 32
#define NP 64
#define TT 20
#define DIMH 64
#define TOTAL_E (GG * NP * NP * TT)   // 2,621,440
#define TILES_PER_WAVE 8               // 32 elements per tile -> 256 el/wave

static constexpr float EPSV = 1e-5f;
static constexpr float SENSING_R = 2.0f;

typedef __attribute__((ext_vector_type(8)))  short    bf16x8;   // 4 VGPRs = 8 bf16 (MFMA A/B)
typedef __attribute__((ext_vector_type(16))) float    f32x16;   // MFMA C/D
typedef __attribute__((ext_vector_type(4)))  unsigned u32x4;

// pack two f32 -> one u32 of 2 bf16 (lo = src0, hi = src1); no builtin on gfx950 (m240)
static __device__ __forceinline__ unsigned cvtpk(float lo, float hi) {
    unsigned r;
    asm("v_cvt_pk_bf16_f32 %0, %1, %2" : "=v"(r) : "v"(lo), "v"(hi));
    return r;
}
static __device__ __forceinline__ float bflo2f(unsigned w) { return __uint_as_float(w << 16); }
static __device__ __forceinline__ float bfhi2f(unsigned w) { return __uint_as_float(w & 0xffff0000u); }
static __device__ __forceinline__ float lrelu(float x) { return fmaxf(x, 0.1f * x); }

// Layer-1 A fragment: A[row=n, kslot] for one 32-n half, triple-packed split:
//   hi=0 lanes: k0-3 = W1_hi, k4-7 = W1_hi (pairs feat_lo); hi=1: k8-11 = W1_lo (pairs feat_hi)
// 32x32x16 A layout: lane l holds row=l&31, k = 8*(l>>5)+j (word w = k {2w,2w+1})
static __device__ __forceinline__ bf16x8 makeA1(const float* W1, int n, int hi) {
    float c0 = W1[0 * DIMH + n], c1 = W1[1 * DIMH + n], c2 = W1[2 * DIMH + n], c3 = W1[3 * DIMH + n];
    unsigned wh0 = cvtpk(c0, c1), wh1 = cvtpk(c2, c3);
    unsigned wl0 = cvtpk(c0 - bflo2f(wh0), c1 - bfhi2f(wh0));
    unsigned wl1 = cvtpk(c2 - bflo2f(wh1), c3 - bfhi2f(wh1));
    u32x4 p;
    p.x = hi ? wl0 : wh0;  p.y = hi ? wl1 : wh1;
    p.z = hi ? 0u  : wh0;  p.w = hi ? 0u  : wh1;
    return __builtin_bit_cast(bf16x8, p);
}

// Channel-pair base held in u-word m (from verified D layout: row=(r&3)+8*(r>>2)+4hi):
//   u[m] holds channels (tab[m]+4hi, tab[m]+4hi+1); m>=8 -> H2 (+32 baked into tab)
// Layer-2 k-slot K = 16c + 8hi + 2w + eps consumes u-word m=4c+w
//   => W2-row for that slot is ch(K) = tab[4c+w] + 4hi + eps (bijective over 0..63)
// Layer-2 A chunk C: A[row=m_out(<4), k_local=8hi+jj] = scale*W2[ch][m_out]; rows 4-31 zero
// scale: lrelu(h) = 0.55h + 0.45|h|  ->  two fragment sets (0.55*W2, 0.45*W2)
template <int C>
static __device__ __forceinline__ bf16x8 makeWA(const float* W2, int hi, int l31, float scale) {
    constexpr int tab[16] = {0,2,8,10,16,18,24,26,32,34,40,42,48,50,56,58};
    const bool mv = (l31 < 4);
    float q[8];
#pragma unroll
    for (int jj = 0; jj < 8; ++jj) {
        const int ch = tab[4 * C + (jj >> 1)] + 4 * hi + (jj & 1);
        q[jj] = mv ? scale * W2[ch * 4 + l31] : 0.0f;
    }
    u32x4 p;
    p.x = cvtpk(q[0], q[1]); p.y = cvtpk(q[2], q[3]);
    p.z = cvtpk(q[4], q[5]); p.w = cvtpk(q[6], q[7]);
    return __builtin_bit_cast(bf16x8, p);
}

__global__ __launch_bounds__(256) void social_mfma_kernel(
    const float* __restrict__ traj,    // [G*N, T, 2]
    const float* __restrict__ speed,   // [G*N, T, 2]
    const float* __restrict__ W1,      // [4, 64]
    const float* __restrict__ b1,      // [64]
    const float* __restrict__ W2,      // [64, 4]
    const float* __restrict__ b2,      // [4]
    const float* __restrict__ W3,      // [4, 2]
    const float* __restrict__ b3,      // [2]
    float* __restrict__ out_mask,      // [G,N,N,T] 0/1 floats
    float* __restrict__ out_vec,       // [G,N,N,T,2]
    float cos_half_thr)
{
    const int tid  = threadIdx.x;
    const int lane = tid & 63;
    const int l31  = lane & 31;
    const int hi   = lane >> 5;
    const int wgid = blockIdx.x * 4 + (tid >> 6);
    const int e0   = wgid * (TILES_PER_WAVE * 32);

    // ---- one-time per-wave weight fragments ----
    const bf16x8 A1 = makeA1(W1, l31, hi);         // channels 0..31
    const bf16x8 A2 = makeA1(W1, 32 + l31, hi);    // channels 32..63
    const bf16x8 WA0a = makeWA<0>(W2, hi, l31, 0.55f);
    const bf16x8 WA1a = makeWA<1>(W2, hi, l31, 0.55f);
    const bf16x8 WA2a = makeWA<2>(W2, hi, l31, 0.55f);
    const bf16x8 WA3a = makeWA<3>(W2, hi, l31, 0.55f);
    const bf16x8 WA0b = makeWA<0>(W2, hi, l31, 0.45f);
    const bf16x8 WA1b = makeWA<1>(W2, hi, l31, 0.45f);
    const bf16x8 WA2b = makeWA<2>(W2, hi, l31, 0.45f);
    const bf16x8 WA3b = makeWA<3>(W2, hi, l31, 0.45f);

    // bias fragments: C/D row = (r&3)+8*(r>>2)+4*hi, col = lane&31 (m74/m101 verified)
    f32x16 C1, C2;
#pragma unroll
    for (int r = 0; r < 16; ++r) {
        int n = (r & 3) + 8 * (r >> 2) + 4 * hi;
        C1[r] = b1[n];
        C2[r] = b1[n + 32];
    }
    f32x16 CY0 = {};   // layer2 C-in: b2 on rows m=0..3 (hi=0, regs 0..3), else 0
    if (hi == 0) { CY0[0] = b2[0]; CY0[1] = b2[1]; CY0[2] = b2[2]; CY0[3] = b2[3]; }

    const float w300 = W3[0], w301 = W3[1], w310 = W3[2], w311 = W3[3];
    const float w320 = W3[4], w321 = W3[5], w330 = W3[6], w331 = W3[7];
    const float bo0 = b3[0], bo1 = b3[1];

#pragma unroll 1
    for (int tile = 0; tile < TILES_PER_WAVE; ++tile) {
        // element for this lane: both half-waves mirror the same 32 elements
        const int e   = e0 + tile * 32 + l31;
        const int t   = e % TT;
        const int q20 = e / TT;            // = gi*64 + j
        const int j   = q20 & 63;
        const int gi  = q20 >> 6;
        const int pjr = (gi & ~63) + j;    // g*64 + j

        const float2 Pi = *reinterpret_cast<const float2*>(traj  + (gi  * TT + t) * 2);
        const float2 Vi = *reinterpret_cast<const float2*>(speed + (gi  * TT + t) * 2);
        const float2 Pj = *reinterpret_cast<const float2*>(traj  + (pjr * TT + t) * 2);
        const float vecx = Pj.x - Pi.x, vecy = Pj.y - Pi.y;
        const float vix = Vi.x, viy = Vi.y;

        // ---- layer1 B fragment (feat^T), split fh/fl; kslots {fh,fl | fh,0} ----
        unsigned f0 = cvtpk(vecx, vecy), f1 = cvtpk(vix, viy);
        unsigned f2 = cvtpk(vecx - bflo2f(f0), vecy - bfhi2f(f0));
        unsigned f3 = cvtpk(vix  - bflo2f(f1), viy  - bfhi2f(f1));
        u32x4 bp;
        bp.x = f0; bp.y = f1;
        bp.z = hi ? 0u : f2; bp.w = hi ? 0u : f3;
        const bf16x8 Bf = __builtin_bit_cast(bf16x8, bp);

        // ---- layer1: h^T[n, e] = W1^T·feat^T + b1 (PRE-activation) ----
        f32x16 H1 = __builtin_amdgcn_mfma_f32_32x32x16_bf16(A1, Bf, C1, 0, 0, 0);
        f32x16 H2 = __builtin_amdgcn_mfma_f32_32x32x16_bf16(A2, Bf, C2, 0, 0, 0);

        // ---- pack RAW h to bf16 pair-words; |h| = sign-mask (exact bf16 abs) ----
        unsigned u[16], v[16];
#pragma unroll
        for (int m = 0; m < 8; ++m) {
            u[m]     = cvtpk(H1[2 * m], H1[2 * m + 1]);
            u[8 + m] = cvtpk(H2[2 * m], H2[2 * m + 1]);
        }
#pragma unroll
        for (int m = 0; m < 16; ++m) v[m] = u[m] & 0x7fff7fffu;

        // ---- layer2: y = (0.55*W2)·h + (0.45*W2)·|h| + b2 ----
        // two independent 4-MFMA chains (same critical depth as before)
        f32x16 Ya = CY0;
        f32x16 Yb = {};
#define L2STEP(acc, c, WAc, src)                                               \
        {                                                                      \
            u32x4 bb;                                                          \
            bb.x = src[4 * c + 0]; bb.y = src[4 * c + 1];                      \
            bb.z = src[4 * c + 2]; bb.w = src[4 * c + 3];                      \
            bf16x8 B2 = __builtin_bit_cast(bf16x8, bb);                        \
            acc = __builtin_amdgcn_mfma_f32_32x32x16_bf16(WAc, B2, acc, 0, 0, 0); \
        }
        L2STEP(Ya, 0, WA0a, u) L2STEP(Yb, 0, WA0b, v)
        L2STEP(Ya, 1, WA1a, u) L2STEP(Yb, 1, WA1b, v)
        L2STEP(Ya, 2, WA2a, u) L2STEP(Yb, 2, WA2b, v)
        L2STEP(Ya, 3, WA3a, u) L2STEP(Yb, 3, WA3b, v)
#undef L2STEP

        // ---- epilogue: lanes<32 hold y[m=0..3] for element e in Ya+Yb[0..3] ----
        if (hi == 0) {
            float y0 = lrelu(Ya[0] + Yb[0]) + vecx;
            float y1 = lrelu(Ya[1] + Yb[1]) + vecy;
            float y2 = lrelu(Ya[2] + Yb[2]) + vix;
            float y3 = lrelu(Ya[3] + Yb[3]) + viy;

            float o0 = bo0, o1 = bo1;
            o0 = fmaf(y0, w300, o0);  o1 = fmaf(y0, w301, o1);
            o0 = fmaf(y1, w310, o0);  o1 = fmaf(y1, w311, o1);
            o0 = fmaf(y2, w320, o0);  o1 = fmaf(y2, w321, o1);
            o0 = fmaf(y3, w330, o0);  o1 = fmaf(y3, w331, o1);
            o0 = __fdividef(1.0f, 1.0f + __expf(-o0));
            o1 = __fdividef(1.0f, 1.0f + __expf(-o1));

            // mask: bit-identical expressions to the passing R1/R4/R5 kernels
            float spd  = sqrtf(vix * vix + viy * viy) + EPSV;
            float d2   = vecx * vecx + vecy * vecy;
            float dist = sqrtf(d2);
            float dot  = (vix * vecx + viy * vecy) / (dist + EPSV);
            float r    = dot / spd;
            r = fminf(1.0f, fmaxf(-1.0f, r));
            float mk = (dist <= SENSING_R && r >= cos_half_thr) ? 1.0f : 0.0f;

            out_mask[e] = mk;
            *reinterpret_cast<float2*>(out_vec + 2 * e) = make_float2(o0, o1);
        }
    }
}

extern "C" void kernel_launch(void* const* d_in, const int* in_sizes, int n_in,
                              void* d_out, int out_size, void* d_ws, size_t ws_size,
                              hipStream_t stream) {
    // setup_inputs() order: traj, speed, seq_start_end, W1, b1, W2, b2, W3, b3
    const float* traj  = (const float*)d_in[0];
    const float* speed = (const float*)d_in[1];
    // d_in[2] = seq_start_end — groups contiguous & equal, unused
    const float* W1 = (const float*)d_in[3];
    const float* b1 = (const float*)d_in[4];
    const float* W2 = (const float*)d_in[5];
    const float* b2 = (const float*)d_in[6];
    const float* W3 = (const float*)d_in[7];
    const float* b3 = (const float*)d_in[8];

    float* out_mask = (float*)d_out;          // [G,N,N,T]
    float* out_vec  = out_mask + TOTAL_E;     // [G,N,N,T,2]

    const float cos_half_thr = cosf(0.5f * 0.8333f * 3.1415926f);

    // 1 wave = 256 elements; 4 waves/block => 1024 el/block; grid exact
    const int block = 256;
    const int grid  = TOTAL_E / 1024;         // 2560
    social_mfma_kernel<<<grid, block, 0, stream>>>(
        traj, speed, W1, b1, W2, b2, W3, b3, out_mask, out_vec, cos_half_thr);
}

// Round 16
// 126.190 us; speedup vs baseline: 1.1563x; 1.1563x over previous
//
#include <hip/hip_runtime.h>
#include <math.h>

// Problem constants (match reference)
#define GG 32
#define NP 64
#define TT 20
#define DIMH 64
#define TOTAL_E (GG * NP * NP * TT)   // 2,621,440
#define TILES_PER_WAVE 8               // 32 elements per tile -> 256 el/wave

static constexpr float EPSV = 1e-5f;
static constexpr float SENSING_R = 2.0f;

typedef __attribute__((ext_vector_type(8)))  _Float16 f16x8;    // 4 VGPRs = 8 fp16 (MFMA A/B)
typedef __attribute__((ext_vector_type(16))) float    f32x16;   // MFMA C/D
typedef __attribute__((ext_vector_type(4)))  unsigned u32x4;

// pack two f32 -> one u32 of 2 fp16 (lo -> [15:0]), round-toward-zero
static __device__ __forceinline__ unsigned pkrtz(float lo, float hi) {
    unsigned r;
    asm("v_cvt_pkrtz_f16_f32 %0, %1, %2" : "=v"(r) : "v"(lo), "v"(hi));
    return r;
}
// packed leaky-relu on 2 fp16: max(x, 0.1*x) per half  (0.1h = 0x2E66)
static __device__ __forceinline__ unsigned pk_lrelu(unsigned x, unsigned c01) {
    unsigned t, r;
    asm("v_pk_mul_f16 %0, %1, %2" : "=v"(t) : "v"(x), "v"(c01));
    asm("v_pk_max_f16 %0, %1, %2" : "=v"(r) : "v"(x), "v"(t));
    return r;
}
// host-independent scalar fp16 pack (prologue only; RTE via _Float16 cast)
static __device__ __forceinline__ unsigned pack2h(float a, float b) {
    unsigned la = (unsigned)__builtin_bit_cast(unsigned short, (_Float16)a);
    unsigned lb = (unsigned)__builtin_bit_cast(unsigned short, (_Float16)b);
    return la | (lb << 16);
}
static __device__ __forceinline__ float f16lo2f(unsigned w) {
    return (float)__builtin_bit_cast(_Float16, (unsigned short)(w & 0xffffu));
}
static __device__ __forceinline__ float f16hi2f(unsigned w) {
    return (float)__builtin_bit_cast(_Float16, (unsigned short)(w >> 16));
}
static __device__ __forceinline__ float lrelu(float x) { return fmaxf(x, 0.1f * x); }

// Layer-1 A fragment (fp16, hi/lo split; same k-slot scheme as validated bf16 version):
//   hi=0 lanes: k0-3 = W1_hi, k4-7 = W1_hi (pairs feat_lo); hi=1: k8-11 = W1_lo (pairs feat_hi)
// 32x32x16 A layout: lane l holds row=l&31, k = 8*(l>>5)+j (word w = k {2w,2w+1})
static __device__ __forceinline__ f16x8 makeA1(const float* W1, int n, int hi) {
    float c0 = W1[0 * DIMH + n], c1 = W1[1 * DIMH + n], c2 = W1[2 * DIMH + n], c3 = W1[3 * DIMH + n];
    unsigned wh0 = pack2h(c0, c1), wh1 = pack2h(c2, c3);
    unsigned wl0 = pack2h(c0 - f16lo2f(wh0), c1 - f16hi2f(wh0));
    unsigned wl1 = pack2h(c2 - f16lo2f(wh1), c3 - f16hi2f(wh1));
    u32x4 p;
    p.x = hi ? wl0 : wh0;  p.y = hi ? wl1 : wh1;
    p.z = hi ? 0u  : wh0;  p.w = hi ? 0u  : wh1;
    return __builtin_bit_cast(f16x8, p);
}

// Channel-pair base held in u-word m (validated D layout: row=(r&3)+8*(r>>2)+4hi):
//   u[m] holds channels (tab[m]+4hi, tab[m]+4hi+1); m>=8 -> H2 (+32 baked into tab)
// Layer-2 k-slot K = 16c + 8hi + 2w + eps consumes u-word m=4c+w
//   => W2-row ch(K) = tab[4c+w] + 4hi + eps (bijective over 0..63) — permutation baked here
template <int C>
static __device__ __forceinline__ f16x8 makeWA(const float* W2, int hi, int l31) {
    constexpr int tab[16] = {0,2,8,10,16,18,24,26,32,34,40,42,48,50,56,58};
    const bool mv = (l31 < 4);
    float q[8];
#pragma unroll
    for (int jj = 0; jj < 8; ++jj) {
        const int ch = tab[4 * C + (jj >> 1)] + 4 * hi + (jj & 1);
        q[jj] = mv ? W2[ch * 4 + l31] : 0.0f;
    }
    u32x4 p;
    p.x = pack2h(q[0], q[1]); p.y = pack2h(q[2], q[3]);
    p.z = pack2h(q[4], q[5]); p.w = pack2h(q[6], q[7]);
    return __builtin_bit_cast(f16x8, p);
}

__global__ __launch_bounds__(256) void social_mfma_kernel(
    const float* __restrict__ traj,    // [G*N, T, 2]
    const float* __restrict__ speed,   // [G*N, T, 2]
    const float* __restrict__ W1,      // [4, 64]
    const float* __restrict__ b1,      // [64]
    const float* __restrict__ W2,      // [64, 4]
    const float* __restrict__ b2,      // [4]
    const float* __restrict__ W3,      // [4, 2]
    const float* __restrict__ b3,      // [2]
    float* __restrict__ out_mask,      // [G,N,N,T] 0/1 floats
    float* __restrict__ out_vec,       // [G,N,N,T,2]
    float cos_half_thr)
{
    const int tid  = threadIdx.x;
    const int lane = tid & 63;
    const int l31  = lane & 31;
    const int hi   = lane >> 5;
    const int wgid = blockIdx.x * 4 + (tid >> 6);
    const int e0   = wgid * (TILES_PER_WAVE * 32);

    // ---- one-time per-wave weight fragments (fp16) ----
    const f16x8 A1 = makeA1(W1, l31, hi);         // channels 0..31
    const f16x8 A2 = makeA1(W1, 32 + l31, hi);    // channels 32..63
    const f16x8 WA0 = makeWA<0>(W2, hi, l31);
    const f16x8 WA1 = makeWA<1>(W2, hi, l31);
    const f16x8 WA2 = makeWA<2>(W2, hi, l31);
    const f16x8 WA3 = makeWA<3>(W2, hi, l31);

    // bias fragments: C/D row = (r&3)+8*(r>>2)+4*hi, col = lane&31 (m74/m101 verified)
    f32x16 C1, C2;
#pragma unroll
    for (int r = 0; r < 16; ++r) {
        int n = (r & 3) + 8 * (r >> 2) + 4 * hi;
        C1[r] = b1[n];
        C2[r] = b1[n + 32];
    }
    f32x16 CY0 = {};   // layer2 C-in: b2 on rows m=0..3 (hi=0, regs 0..3), else 0
    if (hi == 0) { CY0[0] = b2[0]; CY0[1] = b2[1]; CY0[2] = b2[2]; CY0[3] = b2[3]; }

    const float w300 = W3[0], w301 = W3[1], w310 = W3[2], w311 = W3[3];
    const float w320 = W3[4], w321 = W3[5], w330 = W3[6], w331 = W3[7];
    const float bo0 = b3[0], bo1 = b3[1];
    const unsigned C01 = 0x2E662E66u;   // packed fp16 (0.1, 0.1)

#pragma unroll 1
    for (int tile = 0; tile < TILES_PER_WAVE; ++tile) {
        // element for this lane: both half-waves mirror the same 32 elements
        const int e   = e0 + tile * 32 + l31;
        const int t   = e % TT;
        const int q20 = e / TT;            // = gi*64 + j
        const int j   = q20 & 63;
        const int gi  = q20 >> 6;
        const int pjr = (gi & ~63) + j;    // g*64 + j

        const float2 Pi = *reinterpret_cast<const float2*>(traj  + (gi  * TT + t) * 2);
        const float2 Vi = *reinterpret_cast<const float2*>(speed + (gi  * TT + t) * 2);
        const float2 Pj = *reinterpret_cast<const float2*>(traj  + (pjr * TT + t) * 2);
        const float vecx = Pj.x - Pi.x, vecy = Pj.y - Pi.y;
        const float vix = Vi.x, viy = Vi.y;

        // ---- layer1 B fragment (feat^T) fp16, split fh/fl; kslots {fh,fl | fh,0} ----
        unsigned f0 = pkrtz(vecx, vecy), f1 = pkrtz(vix, viy);
        unsigned f2 = pkrtz(vecx - f16lo2f(f0), vecy - f16hi2f(f0));
        unsigned f3 = pkrtz(vix  - f16lo2f(f1), viy  - f16hi2f(f1));
        u32x4 bp;
        bp.x = f0; bp.y = f1;
        bp.z = hi ? 0u : f2; bp.w = hi ? 0u : f3;
        const f16x8 Bf = __builtin_bit_cast(f16x8, bp);

        // ---- layer1: h^T[n, e] = W1^T·feat^T + b1 (PRE-activation, f32 accum) ----
        f32x16 H1 = __builtin_amdgcn_mfma_f32_32x32x16_f16(A1, Bf, C1, 0, 0, 0);
        f32x16 H2 = __builtin_amdgcn_mfma_f32_32x32x16_f16(A2, Bf, C2, 0, 0, 0);

        // ---- pack h to fp16 pairs, leaky-relu PACKED (2 values/inst) ----
        unsigned u[16];
#pragma unroll
        for (int m = 0; m < 8; ++m) {
            u[m]     = pk_lrelu(pkrtz(H1[2 * m], H1[2 * m + 1]), C01);
            u[8 + m] = pk_lrelu(pkrtz(H2[2 * m], H2[2 * m + 1]), C01);
        }

        // ---- layer2: y^T = W2^T·lrelu(h)^T + b2 ; B2 = u-words DIRECTLY (no shuffles) ----
        f32x16 Y = CY0;
#define L2STEP(c, WAc)                                                        \
        {                                                                     \
            u32x4 bb;                                                         \
            bb.x = u[4 * c + 0]; bb.y = u[4 * c + 1];                         \
            bb.z = u[4 * c + 2]; bb.w = u[4 * c + 3];                         \
            f16x8 B2 = __builtin_bit_cast(f16x8, bb);                         \
            Y = __builtin_amdgcn_mfma_f32_32x32x16_f16(WAc, B2, Y, 0, 0, 0);  \
        }
        L2STEP(0, WA0) L2STEP(1, WA1) L2STEP(2, WA2) L2STEP(3, WA3)
#undef L2STEP

        // ---- epilogue: lanes<32 hold y[m=0..3] for element e in Y[0..3] ----
        if (hi == 0) {
            float y0 = lrelu(Y[0]) + vecx;
            float y1 = lrelu(Y[1]) + vecy;
            float y2 = lrelu(Y[2]) + vix;
            float y3 = lrelu(Y[3]) + viy;

            float o0 = bo0, o1 = bo1;
            o0 = fmaf(y0, w300, o0);  o1 = fmaf(y0, w301, o1);
            o0 = fmaf(y1, w310, o0);  o1 = fmaf(y1, w311, o1);
            o0 = fmaf(y2, w320, o0);  o1 = fmaf(y2, w321, o1);
            o0 = fmaf(y3, w330, o0);  o1 = fmaf(y3, w331, o1);
            o0 = __fdividef(1.0f, 1.0f + __expf(-o0));
            o1 = __fdividef(1.0f, 1.0f + __expf(-o1));

            // mask: bit-identical expressions to the passing R1/R4/R5/R11 kernels
            float spd  = sqrtf(vix * vix + viy * viy) + EPSV;
            float d2   = vecx * vecx + vecy * vecy;
            float dist = sqrtf(d2);
            float dot  = (vix * vecx + viy * vecy) / (dist + EPSV);
            float r    = dot / spd;
            r = fminf(1.0f, fmaxf(-1.0f, r));
            float mk = (dist <= SENSING_R && r >= cos_half_thr) ? 1.0f : 0.0f;

            out_mask[e] = mk;
            *reinterpret_cast<float2*>(out_vec + 2 * e) = make_float2(o0, o1);
        }
    }
}

extern "C" void kernel_launch(void* const* d_in, const int* in_sizes, int n_in,
                              void* d_out, int out_size, void* d_ws, size_t ws_size,
                              hipStream_t stream) {
    // setup_inputs() order: traj, speed, seq_start_end, W1, b1, W2, b2, W3, b3
    const float* traj  = (const float*)d_in[0];
    const float* speed = (const float*)d_in[1];
    // d_in[2] = seq_start_end — groups contiguous & equal, unused
    const float* W1 = (const float*)d_in[3];
    const float* b1 = (const float*)d_in[4];
    const float* W2 = (const float*)d_in[5];
    const float* b2 = (const float*)d_in[6];
    const float* W3 = (const float*)d_in[7];
    const float* b3 = (const float*)d_in[8];

    float* out_mask = (float*)d_out;          // [G,N,N,T]
    float* out_vec  = out_mask + TOTAL_E;     // [G,N,N,T,2]

    const float cos_half_thr = cosf(0.5f * 0.8333f * 3.1415926f);

    // 1 wave = 256 elements; 4 waves/block => 1024 el/block; grid exact
    const int block = 256;
    const int grid  = TOTAL_E / 1024;         // 2560
    social_mfma_kernel<<<grid, block, 0, stream>>>(
        traj, speed, W1, b1, W2, b2, W3, b3, out_mask, out_vec, cos_half_thr);
}